// Round 1
// baseline (95.723 us; speedup 1.0000x reference)
//
#include <hip/hip_runtime.h>

#define MM 32768
#define TPB 256
#define RPT 4                    // output bins per thread
#define TILE (TPB * RPT)         // 1024 bins per tile
#define NTILE ((2 * MM) / TILE)  // 64 tiles
#define NSPLIT 32                // K-split blocks per tile -> 2048 blocks
#define WIN (TILE + 256)         // B window per 256-chunk: 1280 dwords

// C[k] = sum_i A[i] * B[k - i].
// Per tile (k0..k0+TILE-1) and 256-wide i-chunk [i0, i0+256):
//   bSh[s] = B[base + s], base = k0 - i0 - 255  (zero outside [0,M))
//   thread t owns bins k = k0 + RPT*t + r, r in [0,RPT)
//   acc[r] += aSh[255 - kp'] * bSh[RPT*t + r + kp'],  kp' = 0..255
// Sliding register window: per group of 4 kp' we need bSh[RPT*t+4g .. +4g+6],
// i.e. one new 16B LDS read per group (16 MACs) plus one 16B broadcast of A.
template <int SPLITP, bool DIRECT>
__global__ __launch_bounds__(TPB) void conv_kernel(
    const int* __restrict__ A, const int* __restrict__ B,
    unsigned long long* __restrict__ ws, int* __restrict__ out)
{
    __shared__ __align__(16) unsigned bSh[WIN];
    __shared__ __align__(16) unsigned aSh[256];

    const int tile  = (int)blockIdx.x / SPLITP;
    const int split = (int)blockIdx.x % SPLITP;
    const int k0 = tile * TILE;
    const int t  = (int)threadIdx.x;

    int iMin = k0 - (MM - 1); if (iMin < 0) iMin = 0;
    int iMax = k0 + TILE - 1; if (iMax > MM - 1) iMax = MM - 1;
    const int c0 = iMin >> 8;
    const int c1 = iMax >> 8;

    unsigned long long acc[RPT];
#pragma unroll
    for (int r = 0; r < RPT; ++r) acc[r] = 0ull;

    for (int c = c0 + split; c <= c1; c += SPLITP) {
        const int i0 = c << 8;
        const int base = k0 - i0 - 255;

        // Stage B window (zero-padded at the triangle edges) and A chunk.
#pragma unroll
        for (int s = t; s < WIN; s += TPB) {
            const int j = base + s;
            bSh[s] = (j >= 0 && j < MM) ? (unsigned)B[j] : 0u;
        }
        aSh[t] = (unsigned)A[i0 + t];  // i0 in [0, M-256]: always in range
        __syncthreads();

        uint4 bv0 = *(const uint4*)&bSh[RPT * t];
#pragma unroll 4
        for (int g = 0; g < 64; ++g) {
            const uint4 bv1 = *(const uint4*)&bSh[RPT * t + 4 * g + 4];
            const uint4 av  = *(const uint4*)&aSh[252 - 4 * g];
            const unsigned bb[8] = {bv0.x, bv0.y, bv0.z, bv0.w,
                                    bv1.x, bv1.y, bv1.z, bv1.w};
            const unsigned aa[4] = {av.w, av.z, av.y, av.x};  // aa[d] = A[i0+255-4g-d]
#pragma unroll
            for (int d = 0; d < 4; ++d) {
#pragma unroll
                for (int r = 0; r < RPT; ++r) {
                    acc[r] += (unsigned long long)aa[d] * bb[d + r];
                }
            }
            bv0 = bv1;
        }
        __syncthreads();
    }

    if (DIRECT) {
#pragma unroll
        for (int r = 0; r < RPT; ++r) {
            out[k0 + RPT * t + r] = (int)(unsigned)acc[r];
        }
    } else {
        unsigned long long* w = ws + k0 + RPT * t;
#pragma unroll
        for (int r = 0; r < RPT; ++r) {
            atomicAdd(&w[r], acc[r]);
        }
    }
}

__global__ __launch_bounds__(TPB) void finalize_kernel(
    const unsigned long long* __restrict__ ws, int* __restrict__ out, int n)
{
    const int i = (int)blockIdx.x * TPB + (int)threadIdx.x;
    if (i < n) out[i] = (int)(unsigned)ws[i];  // exact sum wrapped to int32
}

extern "C" void kernel_launch(void* const* d_in, const int* in_sizes, int n_in,
                              void* d_out, int out_size, void* d_ws, size_t ws_size,
                              hipStream_t stream)
{
    const int* A = (const int*)d_in[0];
    const int* B = (const int*)d_in[1];
    int* out = (int*)d_out;

    const size_t need = (size_t)(2 * MM) * sizeof(unsigned long long);
    if (ws_size >= need) {
        unsigned long long* ws = (unsigned long long*)d_ws;
        hipMemsetAsync(d_ws, 0, need, stream);
        conv_kernel<NSPLIT, false><<<NTILE * NSPLIT, TPB, 0, stream>>>(A, B, ws, out);
        finalize_kernel<<<(out_size + TPB - 1) / TPB, TPB, 0, stream>>>(ws, out, out_size);
    } else {
        // Fallback if workspace is too small: one block per tile, direct write.
        conv_kernel<1, true><<<NTILE, TPB, 0, stream>>>(A, B, nullptr, out);
    }
}